// Round 5
// baseline (36393.948 us; speedup 1.0000x reference)
//
#include <hip/hip_runtime.h>
#include <math.h>

// Problem constants (fixed by reference)
#define DIMD 256
#define KCODES 4096
#define NROWS 65536
#define QN (NROWS * DIMD)   // 16777216 quantized elements

// ---------------- pass1 (bf16 MFMA prune) parameters ----------------
constexpr int P1_BM = 64;      // rows per block
constexpr int P1_BN = 128;     // codes per N-tile
constexpr int NT    = KCODES / P1_BN;   // 32 N-tiles
constexpr int AST2  = 264;     // As row stride in bf16 elems (528 B = 33*16, odd*16 -> conflict-free frags)
constexpr int BST   = 40;      // Bs row stride in bf16 elems (80 B = 5*16, 5 coprime 8)
constexpr float TAU = 6e-3f;   // candidate margin; hard error bound ~1.1e-3 << TAU/2
constexpr int CAP   = 32;      // candidate slots per row

typedef __attribute__((ext_vector_type(8))) short bf16x8;
typedef __attribute__((ext_vector_type(4))) float f32x4;

// RNE float -> bf16 bits (inputs finite; no NaN handling needed)
__device__ __forceinline__ unsigned short f2bf(float f) {
    unsigned int u = __builtin_bit_cast(unsigned int, f);
    u += 0x7fffu + ((u >> 16) & 1u);
    return (unsigned short)(u >> 16);
}

// Opaque barrier: forces v to be a rounded fp32 value (blocks FMA contraction)
__device__ __forceinline__ float opaque(float v) {
    asm volatile("" : "+v"(v));
    return v;
}

// numpy pairwise_sum of 256 fp32 squares, bit-exact replication (see R4 notes)
__device__ __forceinline__ float np_sumsq_256(const float* __restrict__ p) {
    float total = 0.0f;
    #pragma unroll
    for (int half = 0; half < 2; ++half) {
        const float* b = p + half * 128;
        float r[8];
        #pragma unroll
        for (int j = 0; j < 8; ++j) {
            const float v = b[j];
            r[j] = opaque(v * v);
        }
        for (int i = 8; i < 128; i += 8) {
            #pragma unroll
            for (int j = 0; j < 8; ++j) {
                const float v = b[i + j];
                r[j] += opaque(v * v);
            }
        }
        const float res = ((r[0] + r[1]) + (r[2] + r[3])) + ((r[4] + r[5]) + (r[6] + r[7]));
        total = (half == 0) ? res : (total + res);
    }
    return total;
}

// ---------------------------------------------------------------- kernel Sx
__global__ void sx_kernel(const float* __restrict__ x, float* __restrict__ sx) {
    const int row = blockIdx.x * blockDim.x + threadIdx.x;
    sx[row] = np_sumsq_256(x + (size_t)row * DIMD);
}

// ---------------------------------------------------------------- kernel Se
__global__ void se_kernel(const float* __restrict__ emb, float* __restrict__ se) {
    const int k = blockIdx.x * blockDim.x + threadIdx.x;
    se[k] = np_sumsq_256(emb + (size_t)k * DIMD);
}

// ---------------------------------------------------------------- conv emb->bf16
__global__ void conv_emb_kernel(const float* __restrict__ emb, unsigned short* __restrict__ embh) {
    const int i = blockIdx.x * blockDim.x + threadIdx.x;  // float4 index
    const float4 v = ((const float4*)emb)[i];
    ushort4 h;
    h.x = f2bf(v.x); h.y = f2bf(v.y); h.z = f2bf(v.z); h.w = f2bf(v.w);
    ((ushort4*)embh)[i] = h;
}

// ---------------------------------------------------------------- kernel P1
// bf16 MFMA distance prune: d' = se[k] - 2*dot_bf16(x_row, e_k).
// Per block: 64 rows x all 4096 codes (32 N-tiles of 128). Collect candidate
// codes with d' < running_row_min + TAU into per-row global lists.
// Containment is deterministic: |d'_bf - d'_fp32| hard-bounded ~1.1e-3 < TAU/2.
__global__ __launch_bounds__(256, 3)
void pass1_kernel(const float* __restrict__ x, const unsigned short* __restrict__ embh,
                  const float* __restrict__ se, int* __restrict__ cand,
                  int* __restrict__ cnt_out) {
    __shared__ unsigned short As[P1_BM * AST2];   // 33792 B : x rows, bf16, full K=256
    __shared__ unsigned short Bs[P1_BN * BST];    // 10240 B : emb chunk (32 k), bf16
    __shared__ float ses[P1_BN];
    __shared__ float gmin[P1_BM];                 // running row min over prior tiles
    __shared__ float part[P1_BM * 2];             // per-tile partial mins (2 col-wave-groups)
    __shared__ int   cnts[P1_BM];

    const int t    = threadIdx.x;
    const int w    = t >> 6;
    const int lane = t & 63;
    const int quad = lane >> 4;
    const int lm   = lane & 15;
    const int rbase = (w >> 1) * 32;   // wave row offset (2 row-groups)
    const int cbase = (w & 1) * 64;    // wave col offset (2 col-groups)
    const int row0 = blockIdx.x * P1_BM;

    if (t < P1_BM) {
        gmin[t] = INFINITY; cnts[t] = 0;
        part[2 * t] = INFINITY; part[2 * t + 1] = INFINITY;
    }

    // stage A once: rows row0..row0+63, fp32 -> bf16. thread: row t>>2, elems (t&3)*4 + 16j
    {
        const int r = t >> 2, cc = (t & 3) * 4;
        const float* xp = x + (size_t)(row0 + r) * DIMD + cc;
        unsigned short* dst = &As[r * AST2 + cc];
        #pragma unroll
        for (int j = 0; j < 16; ++j) {
            const float4 v = *(const float4*)(xp + 16 * j);
            ushort4 h;
            h.x = f2bf(v.x); h.y = f2bf(v.y); h.z = f2bf(v.z); h.w = f2bf(v.w);
            *(ushort4*)(dst + 16 * j) = h;
        }
    }
    __syncthreads();

    for (int tile = 0; tile < NT; ++tile) {
        const int c0 = tile * P1_BN;

        f32x4 acc[2][4];
        #pragma unroll
        for (int f = 0; f < 2; ++f)
            #pragma unroll
            for (int g = 0; g < 4; ++g) acc[f][g] = (f32x4){0.f, 0.f, 0.f, 0.f};

        for (int ck = 0; ck < 8; ++ck) {
            const int k0 = ck * 32;
            __syncthreads();  // protect Bs (and, at ck==0, part/gmin/ses) from prev readers
            if (ck == 0) {
                if (t < P1_BM) gmin[t] = fminf(gmin[t], fminf(part[2 * t], part[2 * t + 1]));
                if (t < P1_BN) ses[t] = se[c0 + t];
            }
            // stage B chunk: code t>>1, k-half (t&1)*16 (16 bf16 = 32 B)
            {
                const int cr = t >> 1, kk = (t & 1) * 16;
                const unsigned short* ep = embh + (size_t)(c0 + cr) * DIMD + k0 + kk;
                unsigned short* dst = &Bs[cr * BST + kk];
                const uint4 p0 = *(const uint4*)(ep);
                const uint4 p1 = *(const uint4*)(ep + 8);
                *(uint4*)(dst) = p0;
                *(uint4*)(dst + 8) = p1;
            }
            __syncthreads();

            bf16x8 a[2], b[4];
            #pragma unroll
            for (int f = 0; f < 2; ++f)
                a[f] = *(const bf16x8*)&As[(rbase + f * 16 + lm) * AST2 + k0 + quad * 8];
            #pragma unroll
            for (int g = 0; g < 4; ++g)
                b[g] = *(const bf16x8*)&Bs[(cbase + g * 16 + lm) * BST + quad * 8];
            #pragma unroll
            for (int f = 0; f < 2; ++f)
                #pragma unroll
                for (int g = 0; g < 4; ++g)
                    acc[f][g] = __builtin_amdgcn_mfma_f32_16x16x32_bf16(a[f], b[g], acc[f][g], 0, 0, 0);
        }

        // epilogue: d' = se - 2*acc ; C/D layout col=lm (code), row=quad*4+reg
        float d[2][4][4];
        float m8[2][4];
        #pragma unroll
        for (int f = 0; f < 2; ++f)
            #pragma unroll
            for (int reg = 0; reg < 4; ++reg) {
                float mm = INFINITY;
                #pragma unroll
                for (int g = 0; g < 4; ++g) {
                    const float dv = fmaf(-2.0f, acc[f][g][reg], ses[cbase + g * 16 + lm]);
                    d[f][g][reg] = dv;
                    mm = fminf(mm, dv);
                }
                m8[f][reg] = mm;
            }
        // row min across the 16 lm lanes (stays within quad: lm^off < 16)
        #pragma unroll
        for (int off = 1; off < 16; off <<= 1)
            #pragma unroll
            for (int f = 0; f < 2; ++f)
                #pragma unroll
                for (int reg = 0; reg < 4; ++reg)
                    m8[f][reg] = fminf(m8[f][reg], __shfl_xor(m8[f][reg], off, 64));

        // write per-tile partials; collect candidates vs (lagging gmin, own tile min)
        #pragma unroll
        for (int f = 0; f < 2; ++f)
            #pragma unroll
            for (int reg = 0; reg < 4; ++reg) {
                const int r = rbase + f * 16 + quad * 4 + reg;
                if (lm == 0) part[2 * r + (w & 1)] = m8[f][reg];
                const float thr = fminf(gmin[r], m8[f][reg]) + TAU;
                #pragma unroll
                for (int g = 0; g < 4; ++g) {
                    if (d[f][g][reg] < thr) {
                        const int slot = atomicAdd(&cnts[r], 1);
                        if (slot < CAP)
                            cand[(size_t)(row0 + r) * CAP + slot] = c0 + cbase + g * 16 + lm;
                    }
                }
            }
    }
    __syncthreads();
    if (t < P1_BM) cnt_out[row0 + t] = (cnts[t] > CAP) ? -1 : cnts[t];
}

// ---------------------------------------------------------------- kernel P2
// Exact np-semantics re-rank of candidates: dist = fl(fl(sx - 2*dot) + se),
// dot = sequential fp32 FMA chain over d=0..255 (same class as R4's passing
// kernel). One wave per row; lowest-code tie-break.
__global__ void pass2_kernel(const float* __restrict__ x, const float* __restrict__ emb,
                             const float* __restrict__ sx, const float* __restrict__ se,
                             const int* __restrict__ cand, const int* __restrict__ cnt,
                             int* __restrict__ out_idx) {
    const int w = threadIdx.x >> 6, lane = threadIdx.x & 63;
    const int row = blockIdx.x * 4 + w;
    const int n = cnt[row];
    const float sxr = sx[row];
    const float* xp = x + (size_t)row * DIMD;

    float bestd = INFINITY;
    int   bestc = 0x7fffffff;

    if (n >= 1 && n <= CAP) {
        if (lane < n) {
            const int code = cand[(size_t)row * CAP + lane];
            const float* ep = emb + (size_t)code * DIMD;
            float a = 0.0f;
            for (int d4 = 0; d4 < DIMD / 4; ++d4) {
                const float4 xv = ((const float4*)xp)[d4];
                const float4 ev = ((const float4*)ep)[d4];
                a = fmaf(xv.x, ev.x, a);
                a = fmaf(xv.y, ev.y, a);
                a = fmaf(xv.z, ev.z, a);
                a = fmaf(xv.w, ev.w, a);
            }
            const float t1 = sxr - 2.0f * a;   // fl(sx - 2*dot); *2 exact -> fuse harmless
            bestd = t1 + se[code];             // fl(t1 + se)
            bestc = code;
        }
    } else {
        // overflow / safety fallback: full exact scan (ascending per lane)
        for (int c = lane; c < KCODES; c += 64) {
            const float* ep = emb + (size_t)c * DIMD;
            float a = 0.0f;
            for (int d4 = 0; d4 < DIMD / 4; ++d4) {
                const float4 xv = ((const float4*)xp)[d4];
                const float4 ev = ((const float4*)ep)[d4];
                a = fmaf(xv.x, ev.x, a);
                a = fmaf(xv.y, ev.y, a);
                a = fmaf(xv.z, ev.z, a);
                a = fmaf(xv.w, ev.w, a);
            }
            const float t1 = sxr - 2.0f * a;
            const float dd = t1 + se[c];
            if (dd < bestd || (dd == bestd && c < bestc)) { bestd = dd; bestc = c; }
        }
    }
    // wave argmin, lexicographic (value, code): np first-occurrence semantics
    #pragma unroll
    for (int off = 32; off > 0; off >>= 1) {
        const float od = __shfl_down(bestd, off, 64);
        const int   oc = __shfl_down(bestc, off, 64);
        if (od < bestd || (od == bestd && oc < bestc)) { bestd = od; bestc = oc; }
    }
    if (lane == 0) out_idx[row] = bestc;
}

// ---------------------------------------------------------------- kernel Z
__global__ void zero_loss_kernel(float* __restrict__ out) {
    out[QN] = 0.0f;
}

// ---------------------------------------------------------------- kernel C
// gather emb[idx] -> quantized, write indices as float, accumulate loss
__global__ void gather_loss_kernel(const float* __restrict__ x, const float* __restrict__ emb,
                                   const int* __restrict__ idxs, float* __restrict__ out) {
    const int w = threadIdx.x >> 6, lane = threadIdx.x & 63;
    const int row = blockIdx.x * 4 + w;
    const int idx = idxs[row];
    const float4 e4 = ((const float4*)(emb + (size_t)idx * DIMD))[lane];
    const float4 x4 = ((const float4*)(x + (size_t)row * DIMD))[lane];
    ((float4*)(out + (size_t)row * DIMD))[lane] = e4;
    const float dx = e4.x - x4.x, dy = e4.y - x4.y, dz = e4.z - x4.z, dw = e4.w - x4.w;
    float s = dx * dx + dy * dy + dz * dz + dw * dw;
    #pragma unroll
    for (int off = 32; off > 0; off >>= 1) s += __shfl_down(s, off, 64);
    __shared__ float wsum[4];
    if (lane == 0) wsum[w] = s;
    __syncthreads();
    if (threadIdx.x == 0) {
        const float tot = wsum[0] + wsum[1] + wsum[2] + wsum[3];
        atomicAdd(out + QN, tot * (1.25f / (float)QN));
    }
    if (lane == 0) out[QN + 1 + row] = (float)idx;
}

// ---------------------------------------------------------------- launcher
extern "C" void kernel_launch(void* const* d_in, const int* in_sizes, int n_in,
                              void* d_out, int out_size, void* d_ws, size_t ws_size,
                              hipStream_t stream) {
    const float* x   = (const float*)d_in[0];   // [65536, 256]
    const float* emb = (const float*)d_in[1];   // [4096, 256]
    float* out = (float*)d_out;                 // q[16777216] | loss[1] | idx[65536]

    char* ws = (char*)d_ws;
    unsigned short* embh = (unsigned short*)ws;           ws += (size_t)KCODES * DIMD * 2; // 2 MB
    float* sx  = (float*)ws;                              ws += (size_t)NROWS * 4;         // 256 KB
    float* se  = (float*)ws;                              ws += (size_t)KCODES * 4;        // 16 KB
    int*   cand = (int*)ws;                               ws += (size_t)NROWS * CAP * 4;   // 8 MB
    int*   cnt  = (int*)ws;                               ws += (size_t)NROWS * 4;         // 256 KB
    int*   idx  = (int*)ws;                                                                 // 256 KB

    conv_emb_kernel<<<KCODES * DIMD / 4 / 256, 256, 0, stream>>>(emb, embh);
    sx_kernel<<<NROWS / 256, 256, 0, stream>>>(x, sx);
    se_kernel<<<KCODES / 256, 256, 0, stream>>>(emb, se);
    pass1_kernel<<<NROWS / P1_BM, 256, 0, stream>>>(x, embh, se, cand, cnt);
    pass2_kernel<<<NROWS / 4, 256, 0, stream>>>(x, emb, sx, se, cand, cnt, idx);
    zero_loss_kernel<<<1, 1, 0, stream>>>(out);
    gather_loss_kernel<<<NROWS / 4, 256, 0, stream>>>(x, emb, idx, out);
}

// Round 6
// 1993.354 us; speedup vs baseline: 18.2576x; 18.2576x over previous
//
#include <hip/hip_runtime.h>
#include <math.h>

// Problem constants (fixed by reference)
#define DIMD 256
#define KCODES 4096
#define NROWS 65536
#define QN (NROWS * DIMD)   // 16777216 quantized elements

// ---------------- pass1 (bf16 MFMA prune) parameters ----------------
constexpr int P1_BM = 64;      // rows per block
constexpr int P1_BN = 128;     // codes per N-tile
constexpr int NT    = KCODES / P1_BN;   // 32 N-tiles
constexpr int AST2  = 264;     // As row stride in bf16 elems (528 B)
constexpr int BST   = 40;      // Bs row stride in bf16 elems (80 B)
constexpr float TAU = 2.5e-3f; // candidate margin (hard err budget ~1.2e-3; window ~0.56 sigma -> ~10 cands/row)
constexpr int CAP   = 48;      // candidate slots per row (Poisson(10) > 48 ~ never; overflow -> exact fallback)

typedef __attribute__((ext_vector_type(8))) short bf16x8;
typedef __attribute__((ext_vector_type(4))) float f32x4;

// RNE float -> bf16 bits (inputs finite; no NaN handling needed)
__device__ __forceinline__ unsigned short f2bf(float f) {
    unsigned int u = __builtin_bit_cast(unsigned int, f);
    u += 0x7fffu + ((u >> 16) & 1u);
    return (unsigned short)(u >> 16);
}

// Opaque barrier: forces v to be a rounded fp32 value (blocks FMA contraction)
__device__ __forceinline__ float opaque(float v) {
    asm volatile("" : "+v"(v));
    return v;
}

// numpy pairwise_sum of 256 fp32 squares, bit-exact replication (validated R4)
__device__ __forceinline__ float np_sumsq_256(const float* __restrict__ p) {
    float total = 0.0f;
    #pragma unroll
    for (int half = 0; half < 2; ++half) {
        const float* b = p + half * 128;
        float r[8];
        #pragma unroll
        for (int j = 0; j < 8; ++j) {
            const float v = b[j];
            r[j] = opaque(v * v);
        }
        for (int i = 8; i < 128; i += 8) {
            #pragma unroll
            for (int j = 0; j < 8; ++j) {
                const float v = b[i + j];
                r[j] += opaque(v * v);
            }
        }
        const float res = ((r[0] + r[1]) + (r[2] + r[3])) + ((r[4] + r[5]) + (r[6] + r[7]));
        total = (half == 0) ? res : (total + res);
    }
    return total;
}

// ---------------------------------------------------------------- kernel Sx
__global__ void sx_kernel(const float* __restrict__ x, float* __restrict__ sx) {
    const int row = blockIdx.x * blockDim.x + threadIdx.x;
    sx[row] = np_sumsq_256(x + (size_t)row * DIMD);
}

// ---------------------------------------------------------------- kernel Se
__global__ void se_kernel(const float* __restrict__ emb, float* __restrict__ se) {
    const int k = blockIdx.x * blockDim.x + threadIdx.x;
    se[k] = np_sumsq_256(emb + (size_t)k * DIMD);
}

// ---------------------------------------------------------------- conv emb->bf16
__global__ void conv_emb_kernel(const float* __restrict__ emb, unsigned short* __restrict__ embh) {
    const int i = blockIdx.x * blockDim.x + threadIdx.x;  // float4 index
    const float4 v = ((const float4*)emb)[i];
    ushort4 h;
    h.x = f2bf(v.x); h.y = f2bf(v.y); h.z = f2bf(v.z); h.w = f2bf(v.w);
    ((ushort4*)embh)[i] = h;
}

// ---------------------------------------------------------------- kernel P1
// bf16 MFMA distance prune: d' = se[k] - 2*dot_bf16(x_row, e_k).
// Per block: 64 rows x all 4096 codes (32 N-tiles of 128). Collect candidate
// codes with d' < running_row_min + TAU into per-row global lists.
__global__ __launch_bounds__(256, 3)
void pass1_kernel(const float* __restrict__ x, const unsigned short* __restrict__ embh,
                  const float* __restrict__ se, int* __restrict__ cand,
                  int* __restrict__ cnt_out) {
    __shared__ unsigned short As[P1_BM * AST2];   // 33792 B : x rows, bf16, full K=256
    __shared__ unsigned short Bs[P1_BN * BST];    // 10240 B : emb chunk (32 k), bf16
    __shared__ float ses[P1_BN];
    __shared__ float gmin[P1_BM];                 // running row min over PRIOR tiles
    __shared__ float part[P1_BM * 2];             // per-tile partial mins (2 col-wave-groups)
    __shared__ int   cnts[P1_BM];

    const int t    = threadIdx.x;
    const int w    = t >> 6;
    const int lane = t & 63;
    const int quad = lane >> 4;
    const int lm   = lane & 15;
    const int rbase = (w >> 1) * 32;   // wave row offset (2 row-groups)
    const int cbase = (w & 1) * 64;    // wave col offset (2 col-groups)
    const int row0 = blockIdx.x * P1_BM;

    if (t < P1_BM) {
        gmin[t] = INFINITY; cnts[t] = 0;
        part[2 * t] = INFINITY; part[2 * t + 1] = INFINITY;
    }

    // stage A once: rows row0..row0+63, fp32 -> bf16. thread: row t>>2, elems (t&3)*4 + 16j
    {
        const int r = t >> 2, cc = (t & 3) * 4;
        const float* xp = x + (size_t)(row0 + r) * DIMD + cc;
        unsigned short* dst = &As[r * AST2 + cc];
        #pragma unroll
        for (int j = 0; j < 16; ++j) {
            const float4 v = *(const float4*)(xp + 16 * j);
            ushort4 h;
            h.x = f2bf(v.x); h.y = f2bf(v.y); h.z = f2bf(v.z); h.w = f2bf(v.w);
            *(ushort4*)(dst + 16 * j) = h;
        }
    }
    __syncthreads();

    for (int tile = 0; tile < NT; ++tile) {
        const int c0 = tile * P1_BN;

        f32x4 acc[2][4];
        #pragma unroll
        for (int f = 0; f < 2; ++f)
            #pragma unroll
            for (int g = 0; g < 4; ++g) acc[f][g] = (f32x4){0.f, 0.f, 0.f, 0.f};

        for (int ck = 0; ck < 8; ++ck) {
            const int k0 = ck * 32;
            __syncthreads();  // protect Bs/part/gmin/ses from previous readers
            if (ck == 0) {
                // fold previous tile's partials into gmin (part still holds tile-1 values)
                if (t < P1_BM) gmin[t] = fminf(gmin[t], fminf(part[2 * t], part[2 * t + 1]));
                if (t < P1_BN) ses[t] = se[c0 + t];
            }
            // stage B chunk: code t>>1, k-half (t&1)*16 (16 bf16 = 32 B)
            {
                const int cr = t >> 1, kk = (t & 1) * 16;
                const unsigned short* ep = embh + (size_t)(c0 + cr) * DIMD + k0 + kk;
                unsigned short* dst = &Bs[cr * BST + kk];
                const uint4 p0 = *(const uint4*)(ep);
                const uint4 p1 = *(const uint4*)(ep + 8);
                *(uint4*)(dst) = p0;
                *(uint4*)(dst + 8) = p1;
            }
            __syncthreads();

            bf16x8 a[2], b[4];
            #pragma unroll
            for (int f = 0; f < 2; ++f)
                a[f] = *(const bf16x8*)&As[(rbase + f * 16 + lm) * AST2 + k0 + quad * 8];
            #pragma unroll
            for (int g = 0; g < 4; ++g)
                b[g] = *(const bf16x8*)&Bs[(cbase + g * 16 + lm) * BST + quad * 8];
            #pragma unroll
            for (int f = 0; f < 2; ++f)
                #pragma unroll
                for (int g = 0; g < 4; ++g)
                    acc[f][g] = __builtin_amdgcn_mfma_f32_16x16x32_bf16(a[f], b[g], acc[f][g], 0, 0, 0);
        }

        // epilogue: d' = se - 2*acc ; C/D layout col=lm (code), row=quad*4+reg
        float d[2][4][4];
        float m8[2][4];
        #pragma unroll
        for (int f = 0; f < 2; ++f)
            #pragma unroll
            for (int reg = 0; reg < 4; ++reg) {
                float mm = INFINITY;
                #pragma unroll
                for (int g = 0; g < 4; ++g) {
                    const float dv = fmaf(-2.0f, acc[f][g][reg], ses[cbase + g * 16 + lm]);
                    d[f][g][reg] = dv;
                    mm = fminf(mm, dv);
                }
                m8[f][reg] = mm;
            }
        // row min across the 16 lm lanes (stays within quad: lm^off < 16)
        #pragma unroll
        for (int off = 1; off < 16; off <<= 1)
            #pragma unroll
            for (int f = 0; f < 2; ++f)
                #pragma unroll
                for (int reg = 0; reg < 4; ++reg)
                    m8[f][reg] = fminf(m8[f][reg], __shfl_xor(m8[f][reg], off, 64));

        // publish this tile's partial mins, then collect with the TIGHT threshold
        #pragma unroll
        for (int f = 0; f < 2; ++f)
            #pragma unroll
            for (int reg = 0; reg < 4; ++reg) {
                const int r = rbase + f * 16 + quad * 4 + reg;
                if (lm == 0) part[2 * r + (w & 1)] = m8[f][reg];
            }
        __syncthreads();  // make both column-waves' tile mins visible

        #pragma unroll
        for (int f = 0; f < 2; ++f)
            #pragma unroll
            for (int reg = 0; reg < 4; ++reg) {
                const int r = rbase + f * 16 + quad * 4 + reg;
                const float thr = fminf(gmin[r], fminf(part[2 * r], part[2 * r + 1])) + TAU;
                #pragma unroll
                for (int g = 0; g < 4; ++g) {
                    if (d[f][g][reg] < thr) {
                        const int slot = atomicAdd(&cnts[r], 1);
                        if (slot < CAP)
                            cand[(size_t)(row0 + r) * CAP + slot] = c0 + cbase + g * 16 + lm;
                    }
                }
            }
    }
    __syncthreads();
    if (t < P1_BM) cnt_out[row0 + t] = (cnts[t] > CAP) ? -1 : cnts[t];
}

// ---------------------------------------------------------------- kernel P2
// Exact np-semantics re-rank of candidates: dist = fl(fl(sx - 2*dot) + se),
// dot = sequential fp32 FMA chain over d=0..255 (validated by R5's fallback).
// One wave per row; lowest-code tie-break.
__global__ void pass2_kernel(const float* __restrict__ x, const float* __restrict__ emb,
                             const float* __restrict__ sx, const float* __restrict__ se,
                             const int* __restrict__ cand, const int* __restrict__ cnt,
                             int* __restrict__ out_idx) {
    const int w = threadIdx.x >> 6, lane = threadIdx.x & 63;
    const int row = blockIdx.x * 4 + w;
    const int n = cnt[row];
    const float sxr = sx[row];
    const float* xp = x + (size_t)row * DIMD;

    float bestd = INFINITY;
    int   bestc = 0x7fffffff;

    if (n >= 1 && n <= CAP) {
        if (lane < n) {
            const int code = cand[(size_t)row * CAP + lane];
            const float* ep = emb + (size_t)code * DIMD;
            float a = 0.0f;
            for (int d4 = 0; d4 < DIMD / 4; ++d4) {
                const float4 xv = ((const float4*)xp)[d4];
                const float4 ev = ((const float4*)ep)[d4];
                a = fmaf(xv.x, ev.x, a);
                a = fmaf(xv.y, ev.y, a);
                a = fmaf(xv.z, ev.z, a);
                a = fmaf(xv.w, ev.w, a);
            }
            const float t1 = sxr - 2.0f * a;   // fl(sx - 2*dot); *2 exact -> fuse harmless
            bestd = t1 + se[code];             // fl(t1 + se)
            bestc = code;
        }
    } else {
        // overflow / safety fallback: full exact scan (ascending per lane)
        for (int c = lane; c < KCODES; c += 64) {
            const float* ep = emb + (size_t)c * DIMD;
            float a = 0.0f;
            for (int d4 = 0; d4 < DIMD / 4; ++d4) {
                const float4 xv = ((const float4*)xp)[d4];
                const float4 ev = ((const float4*)ep)[d4];
                a = fmaf(xv.x, ev.x, a);
                a = fmaf(xv.y, ev.y, a);
                a = fmaf(xv.z, ev.z, a);
                a = fmaf(xv.w, ev.w, a);
            }
            const float t1 = sxr - 2.0f * a;
            const float dd = t1 + se[c];
            if (dd < bestd || (dd == bestd && c < bestc)) { bestd = dd; bestc = c; }
        }
    }
    // wave argmin, lexicographic (value, code): np first-occurrence semantics
    #pragma unroll
    for (int off = 32; off > 0; off >>= 1) {
        const float od = __shfl_down(bestd, off, 64);
        const int   oc = __shfl_down(bestc, off, 64);
        if (od < bestd || (od == bestd && oc < bestc)) { bestd = od; bestc = oc; }
    }
    if (lane == 0) out_idx[row] = bestc;
}

// ---------------------------------------------------------------- kernel Z
__global__ void zero_loss_kernel(float* __restrict__ out) {
    out[QN] = 0.0f;
}

// ---------------------------------------------------------------- kernel C
// gather emb[idx] -> quantized, write indices as float, accumulate loss
__global__ void gather_loss_kernel(const float* __restrict__ x, const float* __restrict__ emb,
                                   const int* __restrict__ idxs, float* __restrict__ out) {
    const int w = threadIdx.x >> 6, lane = threadIdx.x & 63;
    const int row = blockIdx.x * 4 + w;
    const int idx = idxs[row];
    const float4 e4 = ((const float4*)(emb + (size_t)idx * DIMD))[lane];
    const float4 x4 = ((const float4*)(x + (size_t)row * DIMD))[lane];
    ((float4*)(out + (size_t)row * DIMD))[lane] = e4;
    const float dx = e4.x - x4.x, dy = e4.y - x4.y, dz = e4.z - x4.z, dw = e4.w - x4.w;
    float s = dx * dx + dy * dy + dz * dz + dw * dw;
    #pragma unroll
    for (int off = 32; off > 0; off >>= 1) s += __shfl_down(s, off, 64);
    __shared__ float wsum[4];
    if (lane == 0) wsum[w] = s;
    __syncthreads();
    if (threadIdx.x == 0) {
        const float tot = wsum[0] + wsum[1] + wsum[2] + wsum[3];
        atomicAdd(out + QN, tot * (1.25f / (float)QN));
    }
    if (lane == 0) out[QN + 1 + row] = (float)idx;
}

// ---------------------------------------------------------------- launcher
extern "C" void kernel_launch(void* const* d_in, const int* in_sizes, int n_in,
                              void* d_out, int out_size, void* d_ws, size_t ws_size,
                              hipStream_t stream) {
    const float* x   = (const float*)d_in[0];   // [65536, 256]
    const float* emb = (const float*)d_in[1];   // [4096, 256]
    float* out = (float*)d_out;                 // q[16777216] | loss[1] | idx[65536]

    char* ws = (char*)d_ws;
    unsigned short* embh = (unsigned short*)ws;           ws += (size_t)KCODES * DIMD * 2; // 2 MB
    float* sx  = (float*)ws;                              ws += (size_t)NROWS * 4;         // 256 KB
    float* se  = (float*)ws;                              ws += (size_t)KCODES * 4;        // 16 KB
    int*   cand = (int*)ws;                               ws += (size_t)NROWS * CAP * 4;   // 12.6 MB
    int*   cnt  = (int*)ws;                               ws += (size_t)NROWS * 4;         // 256 KB
    int*   idx  = (int*)ws;                                                                 // 256 KB

    conv_emb_kernel<<<KCODES * DIMD / 4 / 256, 256, 0, stream>>>(emb, embh);
    sx_kernel<<<NROWS / 256, 256, 0, stream>>>(x, sx);
    se_kernel<<<KCODES / 256, 256, 0, stream>>>(emb, se);
    pass1_kernel<<<NROWS / P1_BM, 256, 0, stream>>>(x, embh, se, cand, cnt);
    pass2_kernel<<<NROWS / 4, 256, 0, stream>>>(x, emb, sx, se, cand, cnt, idx);
    zero_loss_kernel<<<1, 1, 0, stream>>>(out);
    gather_loss_kernel<<<NROWS / 4, 256, 0, stream>>>(x, emb, idx, out);
}

// Round 7
// 1144.827 us; speedup vs baseline: 31.7899x; 1.7412x over previous
//
#include <hip/hip_runtime.h>
#include <math.h>

// Problem constants (fixed by reference)
#define DIMD 256
#define KCODES 4096
#define NROWS 65536
#define QN (NROWS * DIMD)   // 16777216 quantized elements

// ---------------- pass1 (bf16 MFMA prune) parameters ----------------
constexpr int P1_BM = 64;      // rows per block
constexpr int P1_BN = 128;     // codes per N-tile
constexpr int NT    = KCODES / P1_BN;   // 32 N-tiles
constexpr int AST2  = 264;     // As row stride in bf16 elems (528 B)
constexpr int BST   = 40;      // Bs row stride in bf16 elems (80 B)
// Dot-scale margin: candidate iff dot > smax_row - TAU2.
// Error stack (dot scale): bf16 operand rounding <=2.3e-4 (worst), np fp32
// quantization ~3e-5, dropped se <=0.8e-5  ->  TAU2 = 7.5e-4 is ~2.8x margin.
constexpr float TAU2 = 7.5e-4f;
constexpr int CAP   = 48;      // candidate slots per row (E[cands]~3.5; overflow -> exact fallback)

typedef __attribute__((ext_vector_type(8))) short bf16x8;
typedef __attribute__((ext_vector_type(4))) float f32x4;

// RNE float -> bf16 bits (inputs finite; no NaN handling needed)
__device__ __forceinline__ unsigned short f2bf(float f) {
    unsigned int u = __builtin_bit_cast(unsigned int, f);
    u += 0x7fffu + ((u >> 16) & 1u);
    return (unsigned short)(u >> 16);
}

// Opaque barrier: forces v to be a rounded fp32 value (blocks FMA contraction)
__device__ __forceinline__ float opaque(float v) {
    asm volatile("" : "+v"(v));
    return v;
}

// numpy pairwise_sum of 256 fp32 squares, bit-exact replication (validated R4)
__device__ __forceinline__ float np_sumsq_256(const float* __restrict__ p) {
    float total = 0.0f;
    #pragma unroll
    for (int half = 0; half < 2; ++half) {
        const float* b = p + half * 128;
        float r[8];
        #pragma unroll
        for (int j = 0; j < 8; ++j) {
            const float v = b[j];
            r[j] = opaque(v * v);
        }
        for (int i = 8; i < 128; i += 8) {
            #pragma unroll
            for (int j = 0; j < 8; ++j) {
                const float v = b[i + j];
                r[j] += opaque(v * v);
            }
        }
        const float res = ((r[0] + r[1]) + (r[2] + r[3])) + ((r[4] + r[5]) + (r[6] + r[7]));
        total = (half == 0) ? res : (total + res);
    }
    return total;
}

// ---------------------------------------------------------------- kernel Sx
__global__ void sx_kernel(const float* __restrict__ x, float* __restrict__ sx) {
    const int row = blockIdx.x * blockDim.x + threadIdx.x;
    sx[row] = np_sumsq_256(x + (size_t)row * DIMD);
}

// ---------------------------------------------------------------- kernel Se
__global__ void se_kernel(const float* __restrict__ emb, float* __restrict__ se) {
    const int k = blockIdx.x * blockDim.x + threadIdx.x;
    se[k] = np_sumsq_256(emb + (size_t)k * DIMD);
}

// ---------------------------------------------------------------- conv emb->bf16
__global__ void conv_emb_kernel(const float* __restrict__ emb, unsigned short* __restrict__ embh) {
    const int i = blockIdx.x * blockDim.x + threadIdx.x;  // float4 index
    const float4 v = ((const float4*)emb)[i];
    ushort4 h;
    h.x = f2bf(v.x); h.y = f2bf(v.y); h.z = f2bf(v.z); h.w = f2bf(v.w);
    ((ushort4*)embh)[i] = h;
}

// ---------------------------------------------------------------- kernel P1
// bf16 MFMA prune, two K-loops:
//   Loop A: compute per-row global max dot (register-only epilogue).
//   Loop B: recompute identical accs; collect codes with dot > smax - TAU2.
// argmin(dist) == argmax(dot) up to the TAU2 error budget (se is sub-ulp).
__global__ __launch_bounds__(256, 3)
void pass1_kernel(const float* __restrict__ x, const unsigned short* __restrict__ embh,
                  int* __restrict__ cand, int* __restrict__ cnt_out) {
    __shared__ unsigned short As[P1_BM * AST2];   // 33792 B : x rows, bf16, full K=256
    __shared__ unsigned short Bs[P1_BN * BST];    // 10240 B : emb chunk (32 k), bf16
    __shared__ float part[P1_BM * 2];             // loop-A cross-wave merge
    __shared__ float smaxf[P1_BM];                // final per-row max dot
    __shared__ int   cnts[P1_BM];

    const int t    = threadIdx.x;
    const int w    = t >> 6;
    const int lane = t & 63;
    const int quad = lane >> 4;
    const int lm   = lane & 15;
    const int rbase = (w >> 1) * 32;   // wave row offset (2 row-groups)
    const int cbase = (w & 1) * 64;    // wave col offset (2 col-groups)
    const int row0 = blockIdx.x * P1_BM;

    if (t < P1_BM) cnts[t] = 0;

    // stage A once: rows row0..row0+63, fp32 -> bf16. thread: row t>>2, elems (t&3)*4 + 16j
    {
        const int r = t >> 2, cc = (t & 3) * 4;
        const float* xp = x + (size_t)(row0 + r) * DIMD + cc;
        unsigned short* dst = &As[r * AST2 + cc];
        #pragma unroll
        for (int j = 0; j < 16; ++j) {
            const float4 v = *(const float4*)(xp + 16 * j);
            ushort4 h;
            h.x = f2bf(v.x); h.y = f2bf(v.y); h.z = f2bf(v.z); h.w = f2bf(v.w);
            *(ushort4*)(dst + 16 * j) = h;
        }
    }
    __syncthreads();

    // ---------------- Loop A: per-row max dot ----------------
    float rm[2][4];
    #pragma unroll
    for (int f = 0; f < 2; ++f)
        #pragma unroll
        for (int reg = 0; reg < 4; ++reg) rm[f][reg] = -INFINITY;

    for (int tile = 0; tile < NT; ++tile) {
        const int c0 = tile * P1_BN;
        f32x4 acc[2][4];
        #pragma unroll
        for (int f = 0; f < 2; ++f)
            #pragma unroll
            for (int g = 0; g < 4; ++g) acc[f][g] = (f32x4){0.f, 0.f, 0.f, 0.f};

        for (int ck = 0; ck < 8; ++ck) {
            const int k0 = ck * 32;
            __syncthreads();  // protect Bs from previous readers
            {
                const int cr = t >> 1, kk = (t & 1) * 16;
                const unsigned short* ep = embh + (size_t)(c0 + cr) * DIMD + k0 + kk;
                unsigned short* dst = &Bs[cr * BST + kk];
                const uint4 p0 = *(const uint4*)(ep);
                const uint4 p1 = *(const uint4*)(ep + 8);
                *(uint4*)(dst) = p0;
                *(uint4*)(dst + 8) = p1;
            }
            __syncthreads();

            bf16x8 a[2], b[4];
            #pragma unroll
            for (int f = 0; f < 2; ++f)
                a[f] = *(const bf16x8*)&As[(rbase + f * 16 + lm) * AST2 + k0 + quad * 8];
            #pragma unroll
            for (int g = 0; g < 4; ++g)
                b[g] = *(const bf16x8*)&Bs[(cbase + g * 16 + lm) * BST + quad * 8];
            #pragma unroll
            for (int f = 0; f < 2; ++f)
                #pragma unroll
                for (int g = 0; g < 4; ++g)
                    acc[f][g] = __builtin_amdgcn_mfma_f32_16x16x32_bf16(a[f], b[g], acc[f][g], 0, 0, 0);
        }
        #pragma unroll
        for (int f = 0; f < 2; ++f)
            #pragma unroll
            for (int reg = 0; reg < 4; ++reg) {
                float mm = fmaxf(fmaxf(acc[0 + f][0][reg], acc[f][1][reg]),
                                 fmaxf(acc[f][2][reg], acc[f][3][reg]));
                rm[f][reg] = fmaxf(rm[f][reg], mm);
            }
    }
    // reduce across the 16 lm lanes (xor stays within quad)
    #pragma unroll
    for (int off = 1; off < 16; off <<= 1)
        #pragma unroll
        for (int f = 0; f < 2; ++f)
            #pragma unroll
            for (int reg = 0; reg < 4; ++reg)
                rm[f][reg] = fmaxf(rm[f][reg], __shfl_xor(rm[f][reg], off, 64));
    if (lm == 0) {
        #pragma unroll
        for (int f = 0; f < 2; ++f)
            #pragma unroll
            for (int reg = 0; reg < 4; ++reg)
                part[2 * (rbase + f * 16 + quad * 4 + reg) + (w & 1)] = rm[f][reg];
    }
    __syncthreads();
    if (t < P1_BM) smaxf[t] = fmaxf(part[2 * t], part[2 * t + 1]);
    __syncthreads();

    float thrv[2][4];
    #pragma unroll
    for (int f = 0; f < 2; ++f)
        #pragma unroll
        for (int reg = 0; reg < 4; ++reg)
            thrv[f][reg] = smaxf[rbase + f * 16 + quad * 4 + reg] - TAU2;

    // ---------------- Loop B: collect candidates ----------------
    for (int tile = 0; tile < NT; ++tile) {
        const int c0 = tile * P1_BN;
        f32x4 acc[2][4];
        #pragma unroll
        for (int f = 0; f < 2; ++f)
            #pragma unroll
            for (int g = 0; g < 4; ++g) acc[f][g] = (f32x4){0.f, 0.f, 0.f, 0.f};

        for (int ck = 0; ck < 8; ++ck) {
            const int k0 = ck * 32;
            __syncthreads();
            {
                const int cr = t >> 1, kk = (t & 1) * 16;
                const unsigned short* ep = embh + (size_t)(c0 + cr) * DIMD + k0 + kk;
                unsigned short* dst = &Bs[cr * BST + kk];
                const uint4 p0 = *(const uint4*)(ep);
                const uint4 p1 = *(const uint4*)(ep + 8);
                *(uint4*)(dst) = p0;
                *(uint4*)(dst + 8) = p1;
            }
            __syncthreads();

            bf16x8 a[2], b[4];
            #pragma unroll
            for (int f = 0; f < 2; ++f)
                a[f] = *(const bf16x8*)&As[(rbase + f * 16 + lm) * AST2 + k0 + quad * 8];
            #pragma unroll
            for (int g = 0; g < 4; ++g)
                b[g] = *(const bf16x8*)&Bs[(cbase + g * 16 + lm) * BST + quad * 8];
            #pragma unroll
            for (int f = 0; f < 2; ++f)
                #pragma unroll
                for (int g = 0; g < 4; ++g)
                    acc[f][g] = __builtin_amdgcn_mfma_f32_16x16x32_bf16(a[f], b[g], acc[f][g], 0, 0, 0);
        }
        #pragma unroll
        for (int f = 0; f < 2; ++f)
            #pragma unroll
            for (int reg = 0; reg < 4; ++reg) {
                const int r = rbase + f * 16 + quad * 4 + reg;
                #pragma unroll
                for (int g = 0; g < 4; ++g) {
                    if (acc[f][g][reg] > thrv[f][reg]) {
                        const int slot = atomicAdd(&cnts[r], 1);
                        if (slot < CAP)
                            cand[(size_t)(row0 + r) * CAP + slot] = c0 + cbase + g * 16 + lm;
                    }
                }
            }
    }
    __syncthreads();
    if (t < P1_BM) cnt_out[row0 + t] = (cnts[t] > CAP) ? -1 : cnts[t];
}

// ---------------------------------------------------------------- kernel P2
// Exact np-semantics re-rank of candidates: dist = fl(fl(sx - 2*dot) + se),
// dot = sequential fp32 FMA chain (validated R5/R6). One wave per row.
__global__ void pass2_kernel(const float* __restrict__ x, const float* __restrict__ emb,
                             const float* __restrict__ sx, const float* __restrict__ se,
                             const int* __restrict__ cand, const int* __restrict__ cnt,
                             int* __restrict__ out_idx) {
    const int w = threadIdx.x >> 6, lane = threadIdx.x & 63;
    const int row = blockIdx.x * 4 + w;
    const int n = cnt[row];
    const float sxr = sx[row];
    const float* xp = x + (size_t)row * DIMD;

    float bestd = INFINITY;
    int   bestc = 0x7fffffff;

    if (n >= 1 && n <= CAP) {
        if (lane < n) {
            const int code = cand[(size_t)row * CAP + lane];
            const float* ep = emb + (size_t)code * DIMD;
            float a = 0.0f;
            for (int d4 = 0; d4 < DIMD / 4; ++d4) {
                const float4 xv = ((const float4*)xp)[d4];
                const float4 ev = ((const float4*)ep)[d4];
                a = fmaf(xv.x, ev.x, a);
                a = fmaf(xv.y, ev.y, a);
                a = fmaf(xv.z, ev.z, a);
                a = fmaf(xv.w, ev.w, a);
            }
            const float t1 = sxr - 2.0f * a;   // fl(sx - 2*dot)
            bestd = t1 + se[code];             // fl(t1 + se)
            bestc = code;
        }
    } else {
        // overflow / safety fallback: full exact scan (ascending per lane)
        for (int c = lane; c < KCODES; c += 64) {
            const float* ep = emb + (size_t)c * DIMD;
            float a = 0.0f;
            for (int d4 = 0; d4 < DIMD / 4; ++d4) {
                const float4 xv = ((const float4*)xp)[d4];
                const float4 ev = ((const float4*)ep)[d4];
                a = fmaf(xv.x, ev.x, a);
                a = fmaf(xv.y, ev.y, a);
                a = fmaf(xv.z, ev.z, a);
                a = fmaf(xv.w, ev.w, a);
            }
            const float t1 = sxr - 2.0f * a;
            const float dd = t1 + se[c];
            if (dd < bestd || (dd == bestd && c < bestc)) { bestd = dd; bestc = c; }
        }
    }
    // wave argmin, lexicographic (value, code): np first-occurrence semantics
    #pragma unroll
    for (int off = 32; off > 0; off >>= 1) {
        const float od = __shfl_down(bestd, off, 64);
        const int   oc = __shfl_down(bestc, off, 64);
        if (od < bestd || (od == bestd && oc < bestc)) { bestd = od; bestc = oc; }
    }
    if (lane == 0) out_idx[row] = bestc;
}

// ---------------------------------------------------------------- kernel Z
__global__ void zero_loss_kernel(float* __restrict__ out) {
    out[QN] = 0.0f;
}

// ---------------------------------------------------------------- kernel C
// gather emb[idx] -> quantized, write indices as float, accumulate loss
__global__ void gather_loss_kernel(const float* __restrict__ x, const float* __restrict__ emb,
                                   const int* __restrict__ idxs, float* __restrict__ out) {
    const int w = threadIdx.x >> 6, lane = threadIdx.x & 63;
    const int row = blockIdx.x * 4 + w;
    const int idx = idxs[row];
    const float4 e4 = ((const float4*)(emb + (size_t)idx * DIMD))[lane];
    const float4 x4 = ((const float4*)(x + (size_t)row * DIMD))[lane];
    ((float4*)(out + (size_t)row * DIMD))[lane] = e4;
    const float dx = e4.x - x4.x, dy = e4.y - x4.y, dz = e4.z - x4.z, dw = e4.w - x4.w;
    float s = dx * dx + dy * dy + dz * dz + dw * dw;
    #pragma unroll
    for (int off = 32; off > 0; off >>= 1) s += __shfl_down(s, off, 64);
    __shared__ float wsum[4];
    if (lane == 0) wsum[w] = s;
    __syncthreads();
    if (threadIdx.x == 0) {
        const float tot = wsum[0] + wsum[1] + wsum[2] + wsum[3];
        atomicAdd(out + QN, tot * (1.25f / (float)QN));
    }
    if (lane == 0) out[QN + 1 + row] = (float)idx;
}

// ---------------------------------------------------------------- launcher
extern "C" void kernel_launch(void* const* d_in, const int* in_sizes, int n_in,
                              void* d_out, int out_size, void* d_ws, size_t ws_size,
                              hipStream_t stream) {
    const float* x   = (const float*)d_in[0];   // [65536, 256]
    const float* emb = (const float*)d_in[1];   // [4096, 256]
    float* out = (float*)d_out;                 // q[16777216] | loss[1] | idx[65536]

    char* ws = (char*)d_ws;
    unsigned short* embh = (unsigned short*)ws;           ws += (size_t)KCODES * DIMD * 2; // 2 MB
    float* sx  = (float*)ws;                              ws += (size_t)NROWS * 4;         // 256 KB
    float* se  = (float*)ws;                              ws += (size_t)KCODES * 4;        // 16 KB
    int*   cand = (int*)ws;                               ws += (size_t)NROWS * CAP * 4;   // 12.6 MB
    int*   cnt  = (int*)ws;                               ws += (size_t)NROWS * 4;         // 256 KB
    int*   idx  = (int*)ws;                                                                 // 256 KB

    conv_emb_kernel<<<KCODES * DIMD / 4 / 256, 256, 0, stream>>>(emb, embh);
    sx_kernel<<<NROWS / 256, 256, 0, stream>>>(x, sx);
    se_kernel<<<KCODES / 256, 256, 0, stream>>>(emb, se);
    pass1_kernel<<<NROWS / P1_BM, 256, 0, stream>>>(x, embh, cand, cnt);
    pass2_kernel<<<NROWS / 4, 256, 0, stream>>>(x, emb, sx, se, cand, cnt, idx);
    zero_loss_kernel<<<1, 1, 0, stream>>>(out);
    gather_loss_kernel<<<NROWS / 4, 256, 0, stream>>>(x, emb, idx, out);
}